// Round 9
// baseline (299.612 us; speedup 1.0000x reference)
//
#include <hip/hip_runtime.h>
#include <hip/hip_bf16.h>
#include <stdint.h>

// Problem constants
#define NB 8
#define NC 256
#define NN 16384
#define KS 32        // gram k-split: 32 chunks of 512

typedef short bf16x8 __attribute__((ext_vector_type(8)));  // 8 bf16 = 4 VGPR
typedef float f32x4  __attribute__((ext_vector_type(4)));
typedef uint32_t u32;

__device__ __forceinline__ unsigned short f2bf(float f) {
  union { float f; unsigned u; } c; c.f = f;
  return (unsigned short)((c.u + 0x7FFFu + ((c.u >> 16) & 1u)) >> 16);  // RNE
}

// pack 8 f32 -> bf16x8 (RNE, same as f2bf)
__device__ __forceinline__ bf16x8 pack8(float4 lo, float4 hi) {
  union { bf16x8 v; __hip_bfloat162 h[4]; } u;
  u.h[0] = __float22bfloat162_rn(make_float2(lo.x, lo.y));
  u.h[1] = __float22bfloat162_rn(make_float2(lo.z, lo.w));
  u.h[2] = __float22bfloat162_rn(make_float2(hi.x, hi.y));
  u.h[3] = __float22bfloat162_rn(make_float2(hi.z, hi.w));
  return u.v;
}

// async global->LDS, 16B per lane; LDS dest is wave-uniform base + lane*16
__device__ __forceinline__ void gload16(const void* g, void* l) {
  __builtin_amdgcn_global_load_lds(
      (const __attribute__((address_space(1))) u32*)g,
      (__attribute__((address_space(3))) u32*)l, 16, 0, 0);
}

// Stage a [128 rows x 64 bf16] tile (row stride ld_bytes) into 16KB of LDS.
// T2 XOR-swizzle applied on the per-lane global source; LDS stays linear.
__device__ __forceinline__ void stage_tile(const char* src, int ld_bytes,
                                           char* lds, int w, int l) {
#pragma unroll
  for (int i = 0; i < 4; ++i) {
    int s = (w * 4 + i) * 64 + l;      // 0..1023 : 16B chunk index
    int row = s >> 3;
    int srcslot = (l & 7) ^ (row & 7);
    gload16(src + (size_t)row * ld_bytes + srcslot * 16,
            lds + (w * 4 + i) * 1024);
  }
}

// m97-style TN GEMM core: C[128,128] += A[128,K] * B[128,K]^T, K = ktiles*64.
__device__ __forceinline__ void gemm_core(const char* A, int lda_b,
                                          const char* Bm, int ldb_b, int ktiles,
                                          char* smem, int tid, f32x4 acc[4][4]) {
  const int w = tid >> 6, l = tid & 63;
  const int wm = w >> 1, wn = w & 1;
  char* As = smem;
  char* Bs = smem + 16384;
  for (int kt = 0; kt < ktiles; ++kt) {
    stage_tile(A + kt * 128, lda_b, As, w, l);
    stage_tile(Bm + kt * 128, ldb_b, Bs, w, l);
    __syncthreads();
#pragma unroll
    for (int ks = 0; ks < 2; ++ks) {
      bf16x8 av[4], bv[4];
      const int kb = ks * 64 + ((l >> 4) << 4);
#pragma unroll
      for (int m = 0; m < 4; ++m) {
        int row = wm * 64 + m * 16 + (l & 15);
        av[m] = *(const bf16x8*)(As + row * 128 + (kb ^ ((row & 7) << 4)));
      }
#pragma unroll
      for (int nq = 0; nq < 4; ++nq) {
        int row = wn * 64 + nq * 16 + (l & 15);
        bv[nq] = *(const bf16x8*)(Bs + row * 128 + (kb ^ ((row & 7) << 4)));
      }
#pragma unroll
      for (int m = 0; m < 4; ++m)
#pragma unroll
        for (int nq = 0; nq < 4; ++nq)
          acc[m][nq] = __builtin_amdgcn_mfma_f32_16x16x32_bf16(
              av[m], bv[nq], acc[m][nq], 0, 0, 0);
    }
    __syncthreads();
  }
}

// ---- scaled fp32 weights: Wcat ([Wq2;Wk2]), WkT, Wv2 -----------------------
__global__ __launch_bounds__(256) void k_prepw2(const float* __restrict__ wqkv,
                                                const float* __restrict__ wdw,
                                                float* __restrict__ Wcat,
                                                float* __restrict__ WkT,
                                                float* __restrict__ Wv2) {
  const int r = blockIdx.x, t = threadIdx.x;
  Wcat[r * 256 + t] = wqkv[r * 256 + t] * wdw[r];
  float kv = wqkv[(256 + r) * 256 + t] * wdw[256 + r];
  Wcat[65536 + r * 256 + t] = kv;
  WkT[t * 256 + r] = kv;
  Wv2[r * 256 + t] = wqkv[(512 + r) * 256 + t] * wdw[512 + r];
}

// ---- phase1: fused gram (blocks 0..511) + convert (blocks 512..4607) -------
// gram block: (mt, ks, b) computes gpart[ks][b][mt*128..+128][0..256]
//   = Xc[mt-rows] @ Xc^T from a 256x64 fp32 staged tile (source-swizzled).
// convert block: two 64x64 transpose tiles (one per 256-thread half) -> xt.
// Gram's MFMA/latency blocks co-schedule with convert's BW streaming; x is
// read once by each role (L3 shares), xb eliminated entirely.
__global__ __launch_bounds__(512, 2) void k_phase1(const float* __restrict__ x,
                                                   float* __restrict__ gpart,
                                                   char* __restrict__ xt) {
  __shared__ __align__(16) char smraw[65536];
  const int bid = blockIdx.x;
  const int tid = threadIdx.x;

  if (bid < 512) {
    // ---------------- gram role ----------------
    float* tile = (float*)smraw;  // [256 rows][64 f32], slot-swizzled
    const int mt = bid & 1, ks = (bid >> 1) & 31, b = bid >> 6;
    const int w = tid >> 6, l = tid & 63;
    const int wm = (w >> 2) & 1, wn = w & 3;   // 2m x 4n waves
    f32x4 acc[4][4];
#pragma unroll
    for (int m = 0; m < 4; ++m)
#pragma unroll
      for (int n = 0; n < 4; ++n) acc[m][n] = (f32x4){0.f, 0.f, 0.f, 0.f};
    const float* x0 = x + (size_t)b * NC * NN + (size_t)ks * 512;

    for (int kt = 0; kt < 8; ++kt) {
      // stage 256x64 fp32, source-swizzled (slot p holds logical p^(row&15))
#pragma unroll
      for (int i = 0; i < 8; ++i) {
        int c = (w * 8 + i) * 64 + l;          // 0..4095 16B chunks
        int row = c >> 4, slot = c & 15;
        int sl = slot ^ (row & 15);
        gload16(x0 + (size_t)row * NN + kt * 64 + sl * 4,
                (char*)tile + (w * 8 + i) * 1024);
      }
      __syncthreads();
#pragma unroll
      for (int ks2 = 0; ks2 < 2; ++ks2) {
        const int s0 = ks2 * 8 + (l >> 4) * 2;  // logical 16B slot pair
        bf16x8 av[4], bv[4];
#pragma unroll
        for (int m = 0; m < 4; ++m) {
          int row = mt * 128 + wm * 64 + m * 16 + (l & 15);
          float4 lo = *(const float4*)&tile[row * 64 + ((s0 ^ (row & 15)) * 4)];
          float4 hi = *(const float4*)&tile[row * 64 + (((s0 + 1) ^ (row & 15)) * 4)];
          av[m] = pack8(lo, hi);
        }
#pragma unroll
        for (int n = 0; n < 4; ++n) {
          int row = wn * 64 + n * 16 + (l & 15);
          float4 lo = *(const float4*)&tile[row * 64 + ((s0 ^ (row & 15)) * 4)];
          float4 hi = *(const float4*)&tile[row * 64 + (((s0 + 1) ^ (row & 15)) * 4)];
          bv[n] = pack8(lo, hi);
        }
#pragma unroll
        for (int m = 0; m < 4; ++m)
#pragma unroll
          for (int n = 0; n < 4; ++n)
            acc[m][n] = __builtin_amdgcn_mfma_f32_16x16x32_bf16(
                av[m], bv[n], acc[m][n], 0, 0, 0);
      }
      __syncthreads();
    }
    float* gp = gpart + ((size_t)(ks * NB + b)) * 65536;
#pragma unroll
    for (int m = 0; m < 4; ++m)
#pragma unroll
      for (int n = 0; n < 4; ++n)
#pragma unroll
        for (int r = 0; r < 4; ++r) {
          int c = mt * 128 + wm * 64 + m * 16 + ((l >> 4) << 2) + r;
          int d = wn * 64 + n * 16 + (l & 15);
          gp[(size_t)c * 256 + d] = acc[m][n][r];
        }
  } else {
    // ---------------- convert role ----------------
    const int ci = bid - 512;
    const int half = tid >> 8, t2 = tid & 255;
    const int ntile = ci & 255, ctile = ((ci >> 8) & 1) * 2 + half, b = ci >> 9;
    float* T = (float*)smraw + half * (64 * 65);
    {
      int r = t2 >> 2, q = (t2 & 3) * 16;
      const float* src = x + ((size_t)(b * NC + ctile * 64 + r)) * NN + ntile * 64 + q;
#pragma unroll
      for (int i = 0; i < 4; ++i) {
        float4 v = *(const float4*)(src + i * 4);
        T[r * 65 + q + i * 4 + 0] = v.x;
        T[r * 65 + q + i * 4 + 1] = v.y;
        T[r * 65 + q + i * 4 + 2] = v.z;
        T[r * 65 + q + i * 4 + 3] = v.w;
      }
    }
    __syncthreads();
    {
      int nl = t2 >> 2, cq = (t2 & 3) * 16;
      unsigned short outv[16] __attribute__((aligned(16)));
#pragma unroll
      for (int i = 0; i < 16; ++i) outv[i] = f2bf(T[(cq + i) * 65 + nl]);
      char* dst = xt + (((size_t)b * NN + ntile * 64 + nl) * NC + ctile * 64 + cq) * 2;
      *(uint4*)(dst) = *(const uint4*)(outv);
      *(uint4*)(dst + 16) = *(const uint4*)(outv + 8);
    }
  }
}

// ---- G[b] = sum_ks gpart (2048 blocks) -------------------------------------
__global__ __launch_bounds__(256) void k_reduceG(const float* __restrict__ gpart,
                                                 float* __restrict__ G) {
  const int t = threadIdx.x, c = blockIdx.x, b = blockIdx.y;
  float s = 0.f;
#pragma unroll
  for (int ks = 0; ks < KS; ++ks)
    s += gpart[(((size_t)ks * NB + b) * 256 + c) * 256 + t];
  G[((size_t)b * 256 + c) * 256 + t] = s;
}

// ---- T12 = Wcat @ G, fused with norms: nqk[b][r] = dot(T12[b][r], Wcat[r]) -
__global__ __launch_bounds__(256) void k_sgT(const float* __restrict__ Wcat,
                                             const float* __restrict__ G,
                                             float* __restrict__ T12,
                                             float* __restrict__ nqk) {
  const int t = threadIdx.x;
  const int r0 = blockIdx.x * 8, b = blockIdx.y;
  const float* Gb = G + (size_t)b * 65536 + t;
  float acc[8] = {0, 0, 0, 0, 0, 0, 0, 0};
#pragma unroll 4
  for (int k = 0; k < 256; ++k) {
    float bv = Gb[(size_t)k * 256];
#pragma unroll
    for (int o = 0; o < 8; ++o) acc[o] += Wcat[(r0 + o) * 256 + k] * bv;
  }
#pragma unroll
  for (int o = 0; o < 8; ++o)
    T12[(size_t)b * 131072 + (size_t)(r0 + o) * 256 + t] = acc[o];
  // norms: per-row dot(acc, Wcat[r]) over t
  __shared__ float red[8][4];
  const int w = t >> 6, l = t & 63;
#pragma unroll
  for (int o = 0; o < 8; ++o) {
    float s = acc[o] * Wcat[(r0 + o) * 256 + t];
#pragma unroll
    for (int off = 32; off; off >>= 1) s += __shfl_xor(s, off);
    if (l == 0) red[o][w] = s;
  }
  __syncthreads();
  if (t < 8)
    nqk[b * 512 + r0 + t] = red[t][0] + red[t][1] + red[t][2] + red[t][3];
}

// ---- S = T1 @ Wk2^T fused with scaling + row-softmax -> attn ---------------
__global__ __launch_bounds__(256) void k_ssoft(const float* __restrict__ T12,
                                               const float* __restrict__ WkT,
                                               const float* __restrict__ nqk,
                                               const float* __restrict__ temp,
                                               float* __restrict__ attn) {
  const int t = threadIdx.x;
  const int c0 = blockIdx.x * 8, b = blockIdx.y;
  const float* Ab = T12 + (size_t)b * 131072 + (size_t)c0 * 256;  // T1 rows
  const float* Bb = WkT + t;
  float acc[8] = {0, 0, 0, 0, 0, 0, 0, 0};
#pragma unroll 4
  for (int k = 0; k < 256; ++k) {
    float bv = Bb[(size_t)k * 256];
#pragma unroll
    for (int o = 0; o < 8; ++o) acc[o] += Ab[o * 256 + k] * bv;
  }
  const float rk = 1.0f / fmaxf(sqrtf(fmaxf(nqk[b * 512 + 256 + t], 0.f)), 1e-12f);
  const float tau = temp[0];
#pragma unroll
  for (int o = 0; o < 8; ++o) {
    float rq = 1.0f / fmaxf(sqrtf(fmaxf(nqk[b * 512 + c0 + o], 0.f)), 1e-12f);
    acc[o] = acc[o] * rq * rk * tau;
  }
  __shared__ float redm[8][4];
  __shared__ float reds[8][4];
  const int w = t >> 6, l = t & 63;
#pragma unroll
  for (int o = 0; o < 8; ++o) {
    float m = acc[o];
#pragma unroll
    for (int off = 32; off; off >>= 1) m = fmaxf(m, __shfl_xor(m, off));
    if (l == 0) redm[o][w] = m;
  }
  __syncthreads();
  float e[8];
#pragma unroll
  for (int o = 0; o < 8; ++o) {
    float m = fmaxf(fmaxf(redm[o][0], redm[o][1]), fmaxf(redm[o][2], redm[o][3]));
    e[o] = __expf(acc[o] - m);
    float s = e[o];
#pragma unroll
    for (int off = 32; off; off >>= 1) s += __shfl_xor(s, off);
    if (l == 0) reds[o][w] = s;
  }
  __syncthreads();
#pragma unroll
  for (int o = 0; o < 8; ++o) {
    float tot = reds[o][0] + reds[o][1] + reds[o][2] + reds[o][3];
    attn[(size_t)b * 65536 + (size_t)(c0 + o) * 256 + t] = e[o] / tot;
  }
}

// ---- fused F = (Wp @ attn) @ Wv2, bf16 out ---------------------------------
__global__ __launch_bounds__(256) void k_sg2x(const float* __restrict__ wp,
                                              const float* __restrict__ attn,
                                              const float* __restrict__ wv2,
                                              char* __restrict__ Fb) {
  __shared__ float P[8 * 256];
  const int t = threadIdx.x;
  const int o0 = blockIdx.x * 8, b = blockIdx.y;
  const float* Ab = wp + (size_t)o0 * 256;
  const float* Bb = attn + (size_t)b * 65536 + t;
  float acc[8] = {0, 0, 0, 0, 0, 0, 0, 0};
#pragma unroll 4
  for (int k = 0; k < 256; ++k) {
    float bv = Bb[(size_t)k * 256];
#pragma unroll
    for (int o = 0; o < 8; ++o) acc[o] += Ab[o * 256 + k] * bv;
  }
#pragma unroll
  for (int o = 0; o < 8; ++o) P[o * 256 + t] = acc[o];
  __syncthreads();
  float a2[8] = {0, 0, 0, 0, 0, 0, 0, 0};
  const float* Bv = wv2 + t;
#pragma unroll 4
  for (int k = 0; k < 256; ++k) {
    float bv = Bv[(size_t)k * 256];
#pragma unroll
    for (int o = 0; o < 8; ++o) a2[o] += P[o * 256 + k] * bv;
  }
  unsigned short* Cp = (unsigned short*)Fb + (size_t)b * 65536;
#pragma unroll
  for (int o = 0; o < 8; ++o) Cp[(size_t)(o0 + o) * 256 + t] = f2bf(a2[o]);
}

// ---- final: out[b][o][n] = F[b] @ x[b] ; outT tiles (round-4 version) ------
__global__ __launch_bounds__(256) void k_final(const char* __restrict__ xt,
                                               const char* __restrict__ fb,
                                               float* __restrict__ out) {
  __shared__ char smem[65536];
  const int tid = threadIdx.x;
  const int nt = blockIdx.x, ot = blockIdx.y, b = blockIdx.z;
  f32x4 acc[4][4];
#pragma unroll
  for (int m = 0; m < 4; ++m)
#pragma unroll
    for (int nq = 0; nq < 4; ++nq) acc[m][nq] = (f32x4){0.f, 0.f, 0.f, 0.f};
  const char* Ap = xt + ((size_t)b * NN + (size_t)nt * 128) * 512;
  const char* Bp = fb + ((size_t)(b * 256 + ot * 128)) * 512;
  gemm_core(Ap, 512, Bp, 512, 4, smem, tid, acc);
  const int w = tid >> 6, l = tid & 63, wm = w >> 1, wn = w & 1;
  // bounce transposed into LDS: [o_local 128][n_local 128] fp32, swizzled
#pragma unroll
  for (int m = 0; m < 4; ++m)
#pragma unroll
    for (int nq = 0; nq < 4; ++nq)
#pragma unroll
      for (int r = 0; r < 4; ++r) {
        int i = wm * 64 + m * 16 + ((l >> 4) << 2) + r;  // n_local (A row)
        int j = wn * 64 + nq * 16 + (l & 15);            // o_local (B row)
        *(float*)(smem + j * 512 + ((i * 4) ^ ((j & 7) << 4))) = acc[m][nq][r];
      }
  __syncthreads();
  const int j = tid >> 1, h = tid & 1;
  float* dst = out + ((size_t)(b * 256 + ot * 128 + j)) * NN + nt * 128;
#pragma unroll
  for (int cc = 0; cc < 16; ++cc) {
    int ch = h * 16 + cc;
    *(uint4*)(dst + ch * 4) =
        *(const uint4*)(smem + j * 512 + ((ch * 16) ^ ((j & 7) << 4)));
  }
}

extern "C" void kernel_launch(void* const* d_in, const int* in_sizes, int n_in,
                              void* d_out, int out_size, void* d_ws, size_t ws_size,
                              hipStream_t stream) {
  const float* x     = (const float*)d_in[0];
  const float* wqkv  = (const float*)d_in[1];
  const float* wdwf  = (const float*)d_in[2];
  const float* temp  = (const float*)d_in[3];
  const float* wproj = (const float*)d_in[4];
  float* out = (float*)d_out;
  char* ws = (char*)d_ws;

  // Workspace layout (bytes); total ~145 MB
  char*  xt    = ws;                            // bf16 [B][N][C]      67,108,864
  float* gpart = (float*)(ws + 67108864);       // f32 [32][B][256][256] 67,108,864
  float* G     = (float*)(ws + 134217728);      // f32 [B][256][256]    2,097,152
  float* T12   = (float*)(ws + 136314880);      // f32 [B][512][256]    4,194,304
  float* attn  = (float*)(ws + 140509184);      // f32 [B][256][256]    2,097,152
  char*  Fb    = ws + 142606336;                // bf16 [B][256][256]   1,048,576
  float* Wcat  = (float*)(ws + 143654912);      // f32 [512][256]         524,288
  float* WkT   = (float*)(ws + 144179200);      // f32 [256][256]         262,144
  float* Wv2   = (float*)(ws + 144441344);      // f32 [256][256]         262,144
  float* nqk   = (float*)(ws + 144703488);      // f32 [B][512]            16,384

  k_prepw2<<<dim3(256), dim3(256), 0, stream>>>(wqkv, wdwf, Wcat, WkT, Wv2);
  // fused gram + convert: one pass over the machine, xb eliminated
  k_phase1<<<dim3(4608), dim3(512), 0, stream>>>(x, gpart, xt);
  k_reduceG<<<dim3(256, NB), dim3(256), 0, stream>>>(gpart, G);
  k_sgT<<<dim3(64, NB), dim3(256), 0, stream>>>(Wcat, G, T12, nqk);
  k_ssoft<<<dim3(32, NB), dim3(256), 0, stream>>>(T12, WkT, nqk, temp, attn);
  k_sg2x<<<dim3(32, NB), dim3(256), 0, stream>>>(wproj, attn, Wv2, Fb);
  k_final<<<dim3(128, 2, NB), dim3(256), 0, stream>>>(xt, Fb, out);
}

// Round 10
// 279.610 us; speedup vs baseline: 1.0715x; 1.0715x over previous
//
#include <hip/hip_runtime.h>
#include <stdint.h>

// Problem constants
#define NB 8
#define NC 256
#define NN 16384
#define KS 32        // gram k-split: 32 chunks of 512

typedef short bf16x8 __attribute__((ext_vector_type(8)));  // 8 bf16 = 4 VGPR
typedef float f32x4  __attribute__((ext_vector_type(4)));
typedef uint32_t u32;

__device__ __forceinline__ unsigned short f2bf(float f) {
  union { float f; unsigned u; } c; c.f = f;
  return (unsigned short)((c.u + 0x7FFFu + ((c.u >> 16) & 1u)) >> 16);  // RNE
}

// async global->LDS, 16B per lane; LDS dest is wave-uniform base + lane*16
__device__ __forceinline__ void gload16(const void* g, void* l) {
  __builtin_amdgcn_global_load_lds(
      (const __attribute__((address_space(1))) u32*)g,
      (__attribute__((address_space(3))) u32*)l, 16, 0, 0);
}

// Stage a [128 rows x 64 bf16] tile (row stride ld_bytes) into 16KB of LDS.
// T2 XOR-swizzle applied on the per-lane global source; LDS stays linear.
__device__ __forceinline__ void stage_tile(const char* src, int ld_bytes,
                                           char* lds, int w, int l) {
#pragma unroll
  for (int i = 0; i < 4; ++i) {
    int s = (w * 4 + i) * 64 + l;      // 0..1023 : 16B chunk index
    int row = s >> 3;
    int srcslot = (l & 7) ^ (row & 7);
    gload16(src + (size_t)row * ld_bytes + srcslot * 16,
            lds + (w * 4 + i) * 1024);
  }
}

// m97-style TN GEMM core: C[128,128] += A[128,K] * B[128,K]^T, K = ktiles*64.
__device__ __forceinline__ void gemm_core(const char* A, int lda_b,
                                          const char* Bm, int ldb_b, int ktiles,
                                          char* smem, int tid, f32x4 acc[4][4]) {
  const int w = tid >> 6, l = tid & 63;
  const int wm = w >> 1, wn = w & 1;
  char* As = smem;
  char* Bs = smem + 16384;
  for (int kt = 0; kt < ktiles; ++kt) {
    stage_tile(A + kt * 128, lda_b, As, w, l);
    stage_tile(Bm + kt * 128, ldb_b, Bs, w, l);
    __syncthreads();
#pragma unroll
    for (int ks = 0; ks < 2; ++ks) {
      bf16x8 av[4], bv[4];
      const int kb = ks * 64 + ((l >> 4) << 4);
#pragma unroll
      for (int m = 0; m < 4; ++m) {
        int row = wm * 64 + m * 16 + (l & 15);
        av[m] = *(const bf16x8*)(As + row * 128 + (kb ^ ((row & 7) << 4)));
      }
#pragma unroll
      for (int nq = 0; nq < 4; ++nq) {
        int row = wn * 64 + nq * 16 + (l & 15);
        bv[nq] = *(const bf16x8*)(Bs + row * 128 + (kb ^ ((row & 7) << 4)));
      }
#pragma unroll
      for (int m = 0; m < 4; ++m)
#pragma unroll
        for (int nq = 0; nq < 4; ++nq)
          acc[m][nq] = __builtin_amdgcn_mfma_f32_16x16x32_bf16(
              av[m], bv[nq], acc[m][nq], 0, 0, 0);
    }
    __syncthreads();
  }
}

// ---- scaled fp32 weights: Wcat ([Wq2;Wk2]), WkT, Wv2 -----------------------
__global__ __launch_bounds__(256) void k_prepw2(const float* __restrict__ wqkv,
                                                const float* __restrict__ wdw,
                                                float* __restrict__ Wcat,
                                                float* __restrict__ WkT,
                                                float* __restrict__ Wv2) {
  const int r = blockIdx.x, t = threadIdx.x;
  Wcat[r * 256 + t] = wqkv[r * 256 + t] * wdw[r];
  float kv = wqkv[(256 + r) * 256 + t] * wdw[256 + r];
  Wcat[65536 + r * 256 + t] = kv;
  WkT[t * 256 + r] = kv;
  Wv2[r * 256 + t] = wqkv[(512 + r) * 256 + t] * wdw[512 + r];
}

// ---- x fp32 -> xb bf16 [b][c][n]  AND  xt bf16 [b][n][c] -------------------
__global__ __launch_bounds__(256) void k_convert(const float* __restrict__ x,
                                                 char* __restrict__ xb,
                                                 char* __restrict__ xt) {
  __shared__ float t[64][65];
  const int tid = threadIdx.x;
  const int ntile = blockIdx.x, ctile = blockIdx.y, b = blockIdx.z;
  {
    int r = tid >> 2, q = (tid & 3) * 16;
    const size_t rowoff = ((size_t)(b * NC + ctile * 64 + r)) * NN + ntile * 64 + q;
    const float* src = x + rowoff;
    unsigned short bv[16] __attribute__((aligned(16)));
#pragma unroll
    for (int i = 0; i < 4; ++i) {
      float4 v = *(const float4*)(src + i * 4);
      t[r][q + i * 4 + 0] = v.x;
      t[r][q + i * 4 + 1] = v.y;
      t[r][q + i * 4 + 2] = v.z;
      t[r][q + i * 4 + 3] = v.w;
      bv[i * 4 + 0] = f2bf(v.x);
      bv[i * 4 + 1] = f2bf(v.y);
      bv[i * 4 + 2] = f2bf(v.z);
      bv[i * 4 + 3] = f2bf(v.w);
    }
    char* dst = xb + rowoff * 2;
    *(uint4*)(dst) = *(const uint4*)(bv);
    *(uint4*)(dst + 16) = *(const uint4*)(bv + 8);
  }
  __syncthreads();
  {
    int nl = tid >> 2, cq = (tid & 3) * 16;
    unsigned short outv[16] __attribute__((aligned(16)));
#pragma unroll
    for (int i = 0; i < 16; ++i) outv[i] = f2bf(t[cq + i][nl]);
    char* dst = xt + (((size_t)b * NN + ntile * 64 + nl) * NC + ctile * 64 + cq) * 2;
    *(uint4*)(dst) = *(const uint4*)(outv);
    *(uint4*)(dst + 16) = *(const uint4*)(outv + 8);
  }
}

// ---- gram3: shared-tile gram. One block per (ks,b); 512 threads = 8 waves
// (2m x 4n). Stage the 256x64 bf16 tile ONCE (32KB, double-buffered); the
// tile serves as BOTH MFMA operands -> 4x fewer staging bytes than the
// quadrant scheme. Full 256x256 fp32 partial out per block.
__global__ __launch_bounds__(512, 2) void k_gram3(const char* __restrict__ xb,
                                                  float* __restrict__ gpart) {
  __shared__ __align__(16) char tile[2][32768];  // [256 rows][128B], dbuf
  const int tid = threadIdx.x;
  const int ks = blockIdx.x, b = blockIdx.y;
  const int w = tid >> 6, l = tid & 63;
  const int wm = w >> 2, wn = w & 3;     // 2m x 4n
  f32x4 acc[8][4];
#pragma unroll
  for (int m = 0; m < 8; ++m)
#pragma unroll
    for (int n = 0; n < 4; ++n) acc[m][n] = (f32x4){0.f, 0.f, 0.f, 0.f};
  // chunk base: rows = channels 0..255, cols = ks*512 + kt*64
  const char* src0 = xb + ((size_t)b * NC * NN + (size_t)ks * 512) * 2;

  // stage one 256x64 bf16 tile: 2048 16B-chunks, 4 per thread
#define STAGE3(buf, kt)                                                     \
  {                                                                         \
    const char* sb = src0 + (kt) * 128;                                     \
    _Pragma("unroll") for (int i = 0; i < 4; ++i) {                         \
      int s = (w * 4 + i) * 64 + l;   /* 0..2047 */                         \
      int row = s >> 3, slot = s & 7;                                       \
      int srcslot = slot ^ (row & 7);                                       \
      gload16(sb + (size_t)row * (NN * 2) + srcslot * 16,                   \
              tile[buf] + (w * 4 + i) * 1024);                              \
    }                                                                       \
  }

  STAGE3(0, 0);
  __syncthreads();
  for (int kt = 0; kt < 8; ++kt) {
    const int cur = kt & 1;
    if (kt < 7) STAGE3(cur ^ 1, kt + 1);   // issue next-tile loads early
    const char* tl = tile[cur];
#pragma unroll
    for (int ks2 = 0; ks2 < 2; ++ks2) {
      const int kb = ks2 * 64 + ((l >> 4) << 4);
      bf16x8 av[8], bv[4];
#pragma unroll
      for (int m = 0; m < 8; ++m) {
        int row = wm * 128 + m * 16 + (l & 15);
        av[m] = *(const bf16x8*)(tl + row * 128 + (kb ^ ((row & 7) << 4)));
      }
#pragma unroll
      for (int n = 0; n < 4; ++n) {
        int row = wn * 64 + n * 16 + (l & 15);
        bv[n] = *(const bf16x8*)(tl + row * 128 + (kb ^ ((row & 7) << 4)));
      }
#pragma unroll
      for (int m = 0; m < 8; ++m)
#pragma unroll
        for (int n = 0; n < 4; ++n)
          acc[m][n] = __builtin_amdgcn_mfma_f32_16x16x32_bf16(
              av[m], bv[n], acc[m][n], 0, 0, 0);
    }
    __syncthreads();   // drains next-tile loads (issued before compute)
  }
#undef STAGE3
  float* gp = gpart + ((size_t)(ks * NB + b)) * 65536;
#pragma unroll
  for (int m = 0; m < 8; ++m)
#pragma unroll
    for (int n = 0; n < 4; ++n)
#pragma unroll
      for (int r = 0; r < 4; ++r) {
        int c = wm * 128 + m * 16 + ((l >> 4) << 2) + r;
        int d = wn * 64 + n * 16 + (l & 15);
        gp[(size_t)c * 256 + d] = acc[m][n][r];
      }
}

// ---- G[b] = sum_ks gpart (2048 blocks) -------------------------------------
__global__ __launch_bounds__(256) void k_reduceG(const float* __restrict__ gpart,
                                                 float* __restrict__ G) {
  const int t = threadIdx.x, c = blockIdx.x, b = blockIdx.y;
  float s = 0.f;
#pragma unroll
  for (int ks = 0; ks < KS; ++ks)
    s += gpart[(((size_t)ks * NB + b) * 256 + c) * 256 + t];
  G[((size_t)b * 256 + c) * 256 + t] = s;
}

// ---- T12 = Wcat @ G, fused with norms: nqk[b][r] = dot(T12[b][r], Wcat[r]) -
__global__ __launch_bounds__(256) void k_sgT(const float* __restrict__ Wcat,
                                             const float* __restrict__ G,
                                             float* __restrict__ T12,
                                             float* __restrict__ nqk) {
  const int t = threadIdx.x;
  const int r0 = blockIdx.x * 8, b = blockIdx.y;
  const float* Gb = G + (size_t)b * 65536 + t;
  float acc[8] = {0, 0, 0, 0, 0, 0, 0, 0};
#pragma unroll 4
  for (int k = 0; k < 256; ++k) {
    float bv = Gb[(size_t)k * 256];
#pragma unroll
    for (int o = 0; o < 8; ++o) acc[o] += Wcat[(r0 + o) * 256 + k] * bv;
  }
#pragma unroll
  for (int o = 0; o < 8; ++o)
    T12[(size_t)b * 131072 + (size_t)(r0 + o) * 256 + t] = acc[o];
  __shared__ float red[8][4];
  const int w = t >> 6, l = t & 63;
#pragma unroll
  for (int o = 0; o < 8; ++o) {
    float s = acc[o] * Wcat[(r0 + o) * 256 + t];
#pragma unroll
    for (int off = 32; off; off >>= 1) s += __shfl_xor(s, off);
    if (l == 0) red[o][w] = s;
  }
  __syncthreads();
  if (t < 8)
    nqk[b * 512 + r0 + t] = red[t][0] + red[t][1] + red[t][2] + red[t][3];
}

// ---- S = T1 @ Wk2^T fused with scaling + row-softmax -> attn ---------------
__global__ __launch_bounds__(256) void k_ssoft(const float* __restrict__ T12,
                                               const float* __restrict__ WkT,
                                               const float* __restrict__ nqk,
                                               const float* __restrict__ temp,
                                               float* __restrict__ attn) {
  const int t = threadIdx.x;
  const int c0 = blockIdx.x * 8, b = blockIdx.y;
  const float* Ab = T12 + (size_t)b * 131072 + (size_t)c0 * 256;  // T1 rows
  const float* Bb = WkT + t;
  float acc[8] = {0, 0, 0, 0, 0, 0, 0, 0};
#pragma unroll 4
  for (int k = 0; k < 256; ++k) {
    float bv = Bb[(size_t)k * 256];
#pragma unroll
    for (int o = 0; o < 8; ++o) acc[o] += Ab[o * 256 + k] * bv;
  }
  const float rk = 1.0f / fmaxf(sqrtf(fmaxf(nqk[b * 512 + 256 + t], 0.f)), 1e-12f);
  const float tau = temp[0];
#pragma unroll
  for (int o = 0; o < 8; ++o) {
    float rq = 1.0f / fmaxf(sqrtf(fmaxf(nqk[b * 512 + c0 + o], 0.f)), 1e-12f);
    acc[o] = acc[o] * rq * rk * tau;
  }
  __shared__ float redm[8][4];
  __shared__ float reds[8][4];
  const int w = t >> 6, l = t & 63;
#pragma unroll
  for (int o = 0; o < 8; ++o) {
    float m = acc[o];
#pragma unroll
    for (int off = 32; off; off >>= 1) m = fmaxf(m, __shfl_xor(m, off));
    if (l == 0) redm[o][w] = m;
  }
  __syncthreads();
  float e[8];
#pragma unroll
  for (int o = 0; o < 8; ++o) {
    float m = fmaxf(fmaxf(redm[o][0], redm[o][1]), fmaxf(redm[o][2], redm[o][3]));
    e[o] = __expf(acc[o] - m);
    float s = e[o];
#pragma unroll
    for (int off = 32; off; off >>= 1) s += __shfl_xor(s, off);
    if (l == 0) reds[o][w] = s;
  }
  __syncthreads();
#pragma unroll
  for (int o = 0; o < 8; ++o) {
    float tot = reds[o][0] + reds[o][1] + reds[o][2] + reds[o][3];
    attn[(size_t)b * 65536 + (size_t)(c0 + o) * 256 + t] = e[o] / tot;
  }
}

// ---- fused F = (Wp @ attn) @ Wv2, bf16 out ---------------------------------
__global__ __launch_bounds__(256) void k_sg2x(const float* __restrict__ wp,
                                              const float* __restrict__ attn,
                                              const float* __restrict__ wv2,
                                              char* __restrict__ Fb) {
  __shared__ float P[8 * 256];
  const int t = threadIdx.x;
  const int o0 = blockIdx.x * 8, b = blockIdx.y;
  const float* Ab = wp + (size_t)o0 * 256;
  const float* Bb = attn + (size_t)b * 65536 + t;
  float acc[8] = {0, 0, 0, 0, 0, 0, 0, 0};
#pragma unroll 4
  for (int k = 0; k < 256; ++k) {
    float bv = Bb[(size_t)k * 256];
#pragma unroll
    for (int o = 0; o < 8; ++o) acc[o] += Ab[o * 256 + k] * bv;
  }
#pragma unroll
  for (int o = 0; o < 8; ++o) P[o * 256 + t] = acc[o];
  __syncthreads();
  float a2[8] = {0, 0, 0, 0, 0, 0, 0, 0};
  const float* Bv = wv2 + t;
#pragma unroll 4
  for (int k = 0; k < 256; ++k) {
    float bv = Bv[(size_t)k * 256];
#pragma unroll
    for (int o = 0; o < 8; ++o) a2[o] += P[o * 256 + k] * bv;
  }
  unsigned short* Cp = (unsigned short*)Fb + (size_t)b * 65536;
#pragma unroll
  for (int o = 0; o < 8; ++o) Cp[(size_t)(o0 + o) * 256 + t] = f2bf(a2[o]);
}

// ---- final: out[b][o][n] = F[b] @ x[b] ; outT tiles (round-4 version) ------
__global__ __launch_bounds__(256) void k_final(const char* __restrict__ xt,
                                               const char* __restrict__ fb,
                                               float* __restrict__ out) {
  __shared__ char smem[65536];
  const int tid = threadIdx.x;
  const int nt = blockIdx.x, ot = blockIdx.y, b = blockIdx.z;
  f32x4 acc[4][4];
#pragma unroll
  for (int m = 0; m < 4; ++m)
#pragma unroll
    for (int nq = 0; nq < 4; ++nq) acc[m][nq] = (f32x4){0.f, 0.f, 0.f, 0.f};
  const char* Ap = xt + ((size_t)b * NN + (size_t)nt * 128) * 512;
  const char* Bp = fb + ((size_t)(b * 256 + ot * 128)) * 512;
  gemm_core(Ap, 512, Bp, 512, 4, smem, tid, acc);
  const int w = tid >> 6, l = tid & 63, wm = w >> 1, wn = w & 1;
#pragma unroll
  for (int m = 0; m < 4; ++m)
#pragma unroll
    for (int nq = 0; nq < 4; ++nq)
#pragma unroll
      for (int r = 0; r < 4; ++r) {
        int i = wm * 64 + m * 16 + ((l >> 4) << 2) + r;  // n_local (A row)
        int j = wn * 64 + nq * 16 + (l & 15);            // o_local (B row)
        *(float*)(smem + j * 512 + ((i * 4) ^ ((j & 7) << 4))) = acc[m][nq][r];
      }
  __syncthreads();
  const int j = tid >> 1, h = tid & 1;
  float* dst = out + ((size_t)(b * 256 + ot * 128 + j)) * NN + nt * 128;
#pragma unroll
  for (int cc = 0; cc < 16; ++cc) {
    int ch = h * 16 + cc;
    *(uint4*)(dst + ch * 4) =
        *(const uint4*)(smem + j * 512 + ((ch * 16) ^ ((j & 7) << 4)));
  }
}

extern "C" void kernel_launch(void* const* d_in, const int* in_sizes, int n_in,
                              void* d_out, int out_size, void* d_ws, size_t ws_size,
                              hipStream_t stream) {
  const float* x     = (const float*)d_in[0];
  const float* wqkv  = (const float*)d_in[1];
  const float* wdwf  = (const float*)d_in[2];
  const float* temp  = (const float*)d_in[3];
  const float* wproj = (const float*)d_in[4];
  float* out = (float*)d_out;
  char* ws = (char*)d_ws;

  // Workspace layout (bytes); total ~212 MB
  char*  xb    = ws;                            // bf16 [B][C][N]      67,108,864
  char*  xt    = ws + 67108864;                 // bf16 [B][N][C]      67,108,864
  float* gpart = (float*)(ws + 134217728);      // f32 [32][B][256][256] 67,108,864
  float* G     = (float*)(ws + 201326592);      // f32 [B][256][256]    2,097,152
  float* T12   = (float*)(ws + 203423744);      // f32 [B][512][256]    4,194,304
  float* attn  = (float*)(ws + 207618048);      // f32 [B][256][256]    2,097,152
  char*  Fb    = ws + 209715200;                // bf16 [B][256][256]   1,048,576
  float* Wcat  = (float*)(ws + 210763776);      // f32 [512][256]         524,288
  float* WkT   = (float*)(ws + 211288064);      // f32 [256][256]         262,144
  float* Wv2   = (float*)(ws + 211550208);      // f32 [256][256]         262,144
  float* nqk   = (float*)(ws + 211812352);      // f32 [B][512]            16,384

  k_prepw2<<<dim3(256), dim3(256), 0, stream>>>(wqkv, wdwf, Wcat, WkT, Wv2);
  k_convert<<<dim3(256, 4, 8), dim3(256), 0, stream>>>(x, xb, xt);
  k_gram3<<<dim3(KS, NB), dim3(512), 0, stream>>>(xb, gpart);
  k_reduceG<<<dim3(256, NB), dim3(256), 0, stream>>>(gpart, G);
  k_sgT<<<dim3(64, NB), dim3(256), 0, stream>>>(Wcat, G, T12, nqk);
  k_ssoft<<<dim3(32, NB), dim3(256), 0, stream>>>(T12, WkT, nqk, temp, attn);
  k_sg2x<<<dim3(32, NB), dim3(256), 0, stream>>>(wproj, attn, Wv2, Fb);
  k_final<<<dim3(128, 2, NB), dim3(256), 0, stream>>>(xt, Fb, out);
}

// Round 11
// 247.368 us; speedup vs baseline: 1.2112x; 1.1303x over previous
//
#include <hip/hip_runtime.h>
#include <hip/hip_bf16.h>
#include <stdint.h>

// Problem constants
#define NB 8
#define NC 256
#define NN 16384
#define KS 32        // gram k-split: 32 chunks of 512

typedef short bf16x8 __attribute__((ext_vector_type(8)));  // 8 bf16 = 4 VGPR
typedef float f32x4  __attribute__((ext_vector_type(4)));
typedef uint32_t u32;

__device__ __forceinline__ unsigned short f2bf(float f) {
  union { float f; unsigned u; } c; c.f = f;
  return (unsigned short)((c.u + 0x7FFFu + ((c.u >> 16) & 1u)) >> 16);  // RNE
}

// pack 8 f32 -> bf16x8 (RNE, same as f2bf)
__device__ __forceinline__ bf16x8 pack8(float4 lo, float4 hi) {
  union { bf16x8 v; __hip_bfloat162 h[4]; } u;
  u.h[0] = __float22bfloat162_rn(make_float2(lo.x, lo.y));
  u.h[1] = __float22bfloat162_rn(make_float2(lo.z, lo.w));
  u.h[2] = __float22bfloat162_rn(make_float2(hi.x, hi.y));
  u.h[3] = __float22bfloat162_rn(make_float2(hi.z, hi.w));
  return u.v;
}

// async global->LDS, 16B per lane; LDS dest is wave-uniform base + lane*16
__device__ __forceinline__ void gload16(const void* g, void* l) {
  __builtin_amdgcn_global_load_lds(
      (const __attribute__((address_space(1))) u32*)g,
      (__attribute__((address_space(3))) u32*)l, 16, 0, 0);
}

// Stage a [128 rows x 64 bf16] tile (row stride ld_bytes) into 16KB of LDS.
// T2 XOR-swizzle applied on the per-lane global source; LDS stays linear.
__device__ __forceinline__ void stage_tile(const char* src, int ld_bytes,
                                           char* lds, int w, int l) {
#pragma unroll
  for (int i = 0; i < 4; ++i) {
    int s = (w * 4 + i) * 64 + l;      // 0..1023 : 16B chunk index
    int row = s >> 3;
    int srcslot = (l & 7) ^ (row & 7);
    gload16(src + (size_t)row * ld_bytes + srcslot * 16,
            lds + (w * 4 + i) * 1024);
  }
}

// m97-style TN GEMM core: C[128,128] += A[128,K] * B[128,K]^T, K = ktiles*64.
__device__ __forceinline__ void gemm_core(const char* A, int lda_b,
                                          const char* Bm, int ldb_b, int ktiles,
                                          char* smem, int tid, f32x4 acc[4][4]) {
  const int w = tid >> 6, l = tid & 63;
  const int wm = w >> 1, wn = w & 1;
  char* As = smem;
  char* Bs = smem + 16384;
  for (int kt = 0; kt < ktiles; ++kt) {
    stage_tile(A + kt * 128, lda_b, As, w, l);
    stage_tile(Bm + kt * 128, ldb_b, Bs, w, l);
    __syncthreads();
#pragma unroll
    for (int ks = 0; ks < 2; ++ks) {
      bf16x8 av[4], bv[4];
      const int kb = ks * 64 + ((l >> 4) << 4);
#pragma unroll
      for (int m = 0; m < 4; ++m) {
        int row = wm * 64 + m * 16 + (l & 15);
        av[m] = *(const bf16x8*)(As + row * 128 + (kb ^ ((row & 7) << 4)));
      }
#pragma unroll
      for (int nq = 0; nq < 4; ++nq) {
        int row = wn * 64 + nq * 16 + (l & 15);
        bv[nq] = *(const bf16x8*)(Bs + row * 128 + (kb ^ ((row & 7) << 4)));
      }
#pragma unroll
      for (int m = 0; m < 4; ++m)
#pragma unroll
        for (int nq = 0; nq < 4; ++nq)
          acc[m][nq] = __builtin_amdgcn_mfma_f32_16x16x32_bf16(
              av[m], bv[nq], acc[m][nq], 0, 0, 0);
    }
    __syncthreads();
  }
}

// ---- scaled fp32 weights: Wcat ([Wq2;Wk2]), WkT, Wv2 -----------------------
__global__ __launch_bounds__(256) void k_prepw2(const float* __restrict__ wqkv,
                                                const float* __restrict__ wdw,
                                                float* __restrict__ Wcat,
                                                float* __restrict__ WkT,
                                                float* __restrict__ Wv2) {
  const int r = blockIdx.x, t = threadIdx.x;
  Wcat[r * 256 + t] = wqkv[r * 256 + t] * wdw[r];
  float kv = wqkv[(256 + r) * 256 + t] * wdw[256 + r];
  Wcat[65536 + r * 256 + t] = kv;
  WkT[t * 256 + r] = kv;
  Wv2[r * 256 + t] = wqkv[(512 + r) * 256 + t] * wdw[512 + r];
}

// ---- gramT: FUSED gram + transpose-convert from ONE staged x tile ----------
// One block per (ks,b); 512 threads = 8 waves (2m x 4n). Per ktile:
//  - stage x fp32 [256c][64n] (64KB, dbuf, 16B-slot-swizzled: phys slot p of
//    row c holds logical slot p^(c&15))
//  - gram: pack8 fragments -> 8x4 MFMA acc (full 256x256 partial per block)
//  - transpose: thread (n4=tid>>5, c8=tid&31) reads 8 swizzled float4 column
//    slices, packs to 4 uint4 bf16 rows of xt[b][n][c] (coalesced 512B runs)
// x read ONCE from HBM; xb/k_convert deleted.
__global__ __launch_bounds__(512, 2) void k_gramT(const float* __restrict__ x,
                                                  float* __restrict__ gpart,
                                                  char* __restrict__ xt) {
  __shared__ __align__(16) float tile[2][256 * 64];  // 2 x 64KB
  const int tid = threadIdx.x;
  const int ks = blockIdx.x, b = blockIdx.y;
  const int w = tid >> 6, l = tid & 63;
  const int wm = w >> 2, wn = w & 3;     // 2m x 4n
  f32x4 acc[8][4];
#pragma unroll
  for (int m = 0; m < 8; ++m)
#pragma unroll
    for (int n = 0; n < 4; ++n) acc[m][n] = (f32x4){0.f, 0.f, 0.f, 0.f};
  const float* x0 = x + (size_t)b * NC * NN + (size_t)ks * 512;

#define STAGET(buf, kt)                                                      \
  {                                                                          \
    _Pragma("unroll") for (int i = 0; i < 8; ++i) {                          \
      int c = (w * 8 + i) * 64 + l;   /* 0..4095 16B chunks */               \
      int row = c >> 4, slot = c & 15;                                       \
      int sl = slot ^ (row & 15);                                            \
      gload16(x0 + (size_t)row * NN + (kt) * 64 + sl * 4,                    \
              (char*)tile[buf] + (w * 8 + i) * 1024);                        \
    }                                                                        \
  }

  STAGET(0, 0);
  __syncthreads();
  for (int kt = 0; kt < 8; ++kt) {
    const int cur = kt & 1;
    if (kt < 7) STAGET(cur ^ 1, kt + 1);   // issue next-tile loads early
    const float* tl = tile[cur];
    // ---- gram MFMA ----
#pragma unroll
    for (int ks2 = 0; ks2 < 2; ++ks2) {
      const int s0 = ks2 * 8 + (l >> 4) * 2;  // logical 16B slot pair
      bf16x8 av[8], bv[4];
#pragma unroll
      for (int m = 0; m < 8; ++m) {
        int row = wm * 128 + m * 16 + (l & 15);
        float4 lo = *(const float4*)&tl[row * 64 + ((s0 ^ (row & 15)) * 4)];
        float4 hi = *(const float4*)&tl[row * 64 + (((s0 + 1) ^ (row & 15)) * 4)];
        av[m] = pack8(lo, hi);
      }
#pragma unroll
      for (int n = 0; n < 4; ++n) {
        int row = wn * 64 + n * 16 + (l & 15);
        float4 lo = *(const float4*)&tl[row * 64 + ((s0 ^ (row & 15)) * 4)];
        float4 hi = *(const float4*)&tl[row * 64 + (((s0 + 1) ^ (row & 15)) * 4)];
        bv[n] = pack8(lo, hi);
      }
#pragma unroll
      for (int m = 0; m < 8; ++m)
#pragma unroll
        for (int n = 0; n < 4; ++n)
          acc[m][n] = __builtin_amdgcn_mfma_f32_16x16x32_bf16(
              av[m], bv[n], acc[m][n], 0, 0, 0);
    }
    // ---- transpose-convert: xt[b][n][c] for this ktile ----
    {
      const int n4 = tid >> 5, c8 = tid & 31;   // n-quad 0..15, c-octet 0..31
      const int gn = ks * 512 + kt * 64 + n4 * 4;
      float vr[8][4];
#pragma unroll
      for (int j = 0; j < 8; ++j) {
        int c = c8 * 8 + j;
        float4 v = *(const float4*)&tl[c * 64 + ((n4 ^ (c & 15)) * 4)];
        vr[j][0] = v.x; vr[j][1] = v.y; vr[j][2] = v.z; vr[j][3] = v.w;
      }
#pragma unroll
      for (int k = 0; k < 4; ++k) {
        unsigned short ov[8] __attribute__((aligned(16)));
#pragma unroll
        for (int j = 0; j < 8; ++j) ov[j] = f2bf(vr[j][k]);
        *(uint4*)(xt + (((size_t)b * NN + gn + k) * 256 + c8 * 8) * 2) =
            *(const uint4*)(ov);
      }
    }
    __syncthreads();   // drains next-tile gloads + all LDS reads of tile[cur]
  }
#undef STAGET
  // ---- gpart epilogue (verbatim r10 gram3) ----
  float* gp = gpart + ((size_t)(ks * NB + b)) * 65536;
#pragma unroll
  for (int m = 0; m < 8; ++m)
#pragma unroll
    for (int n = 0; n < 4; ++n)
#pragma unroll
      for (int r = 0; r < 4; ++r) {
        int c = wm * 128 + m * 16 + ((l >> 4) << 2) + r;
        int d = wn * 64 + n * 16 + (l & 15);
        gp[(size_t)c * 256 + d] = acc[m][n][r];
      }
}

// ---- G[b] = sum_ks gpart (2048 blocks) -------------------------------------
__global__ __launch_bounds__(256) void k_reduceG(const float* __restrict__ gpart,
                                                 float* __restrict__ G) {
  const int t = threadIdx.x, c = blockIdx.x, b = blockIdx.y;
  float s = 0.f;
#pragma unroll
  for (int ks = 0; ks < KS; ++ks)
    s += gpart[(((size_t)ks * NB + b) * 256 + c) * 256 + t];
  G[((size_t)b * 256 + c) * 256 + t] = s;
}

// ---- T12 = Wcat @ G, fused with norms: nqk[b][r] = dot(T12[b][r], Wcat[r]) -
__global__ __launch_bounds__(256) void k_sgT(const float* __restrict__ Wcat,
                                             const float* __restrict__ G,
                                             float* __restrict__ T12,
                                             float* __restrict__ nqk) {
  const int t = threadIdx.x;
  const int r0 = blockIdx.x * 8, b = blockIdx.y;
  const float* Gb = G + (size_t)b * 65536 + t;
  float acc[8] = {0, 0, 0, 0, 0, 0, 0, 0};
#pragma unroll 4
  for (int k = 0; k < 256; ++k) {
    float bv = Gb[(size_t)k * 256];
#pragma unroll
    for (int o = 0; o < 8; ++o) acc[o] += Wcat[(r0 + o) * 256 + k] * bv;
  }
#pragma unroll
  for (int o = 0; o < 8; ++o)
    T12[(size_t)b * 131072 + (size_t)(r0 + o) * 256 + t] = acc[o];
  __shared__ float red[8][4];
  const int w = t >> 6, l = t & 63;
#pragma unroll
  for (int o = 0; o < 8; ++o) {
    float s = acc[o] * Wcat[(r0 + o) * 256 + t];
#pragma unroll
    for (int off = 32; off; off >>= 1) s += __shfl_xor(s, off);
    if (l == 0) red[o][w] = s;
  }
  __syncthreads();
  if (t < 8)
    nqk[b * 512 + r0 + t] = red[t][0] + red[t][1] + red[t][2] + red[t][3];
}

// ---- S = T1 @ Wk2^T fused with scaling + row-softmax -> attn ---------------
__global__ __launch_bounds__(256) void k_ssoft(const float* __restrict__ T12,
                                               const float* __restrict__ WkT,
                                               const float* __restrict__ nqk,
                                               const float* __restrict__ temp,
                                               float* __restrict__ attn) {
  const int t = threadIdx.x;
  const int c0 = blockIdx.x * 8, b = blockIdx.y;
  const float* Ab = T12 + (size_t)b * 131072 + (size_t)c0 * 256;  // T1 rows
  const float* Bb = WkT + t;
  float acc[8] = {0, 0, 0, 0, 0, 0, 0, 0};
#pragma unroll 4
  for (int k = 0; k < 256; ++k) {
    float bv = Bb[(size_t)k * 256];
#pragma unroll
    for (int o = 0; o < 8; ++o) acc[o] += Ab[o * 256 + k] * bv;
  }
  const float rk = 1.0f / fmaxf(sqrtf(fmaxf(nqk[b * 512 + 256 + t], 0.f)), 1e-12f);
  const float tau = temp[0];
#pragma unroll
  for (int o = 0; o < 8; ++o) {
    float rq = 1.0f / fmaxf(sqrtf(fmaxf(nqk[b * 512 + c0 + o], 0.f)), 1e-12f);
    acc[o] = acc[o] * rq * rk * tau;
  }
  __shared__ float redm[8][4];
  __shared__ float reds[8][4];
  const int w = t >> 6, l = t & 63;
#pragma unroll
  for (int o = 0; o < 8; ++o) {
    float m = acc[o];
#pragma unroll
    for (int off = 32; off; off >>= 1) m = fmaxf(m, __shfl_xor(m, off));
    if (l == 0) redm[o][w] = m;
  }
  __syncthreads();
  float e[8];
#pragma unroll
  for (int o = 0; o < 8; ++o) {
    float m = fmaxf(fmaxf(redm[o][0], redm[o][1]), fmaxf(redm[o][2], redm[o][3]));
    e[o] = __expf(acc[o] - m);
    float s = e[o];
#pragma unroll
    for (int off = 32; off; off >>= 1) s += __shfl_xor(s, off);
    if (l == 0) reds[o][w] = s;
  }
  __syncthreads();
#pragma unroll
  for (int o = 0; o < 8; ++o) {
    float tot = reds[o][0] + reds[o][1] + reds[o][2] + reds[o][3];
    attn[(size_t)b * 65536 + (size_t)(c0 + o) * 256 + t] = e[o] / tot;
  }
}

// ---- fused F = (Wp @ attn) @ Wv2, bf16 out ---------------------------------
__global__ __launch_bounds__(256) void k_sg2x(const float* __restrict__ wp,
                                              const float* __restrict__ attn,
                                              const float* __restrict__ wv2,
                                              char* __restrict__ Fb) {
  __shared__ float P[8 * 256];
  const int t = threadIdx.x;
  const int o0 = blockIdx.x * 8, b = blockIdx.y;
  const float* Ab = wp + (size_t)o0 * 256;
  const float* Bb = attn + (size_t)b * 65536 + t;
  float acc[8] = {0, 0, 0, 0, 0, 0, 0, 0};
#pragma unroll 4
  for (int k = 0; k < 256; ++k) {
    float bv = Bb[(size_t)k * 256];
#pragma unroll
    for (int o = 0; o < 8; ++o) acc[o] += Ab[o * 256 + k] * bv;
  }
#pragma unroll
  for (int o = 0; o < 8; ++o) P[o * 256 + t] = acc[o];
  __syncthreads();
  float a2[8] = {0, 0, 0, 0, 0, 0, 0, 0};
  const float* Bv = wv2 + t;
#pragma unroll 4
  for (int k = 0; k < 256; ++k) {
    float bv = Bv[(size_t)k * 256];
#pragma unroll
    for (int o = 0; o < 8; ++o) a2[o] += P[o * 256 + k] * bv;
  }
  unsigned short* Cp = (unsigned short*)Fb + (size_t)b * 65536;
#pragma unroll
  for (int o = 0; o < 8; ++o) Cp[(size_t)(o0 + o) * 256 + t] = f2bf(a2[o]);
}

// ---- final: out[b][o][n] = F[b] @ x[b] ; outT tiles (round-4 version) ------
__global__ __launch_bounds__(256) void k_final(const char* __restrict__ xt,
                                               const char* __restrict__ fb,
                                               float* __restrict__ out) {
  __shared__ char smem[65536];
  const int tid = threadIdx.x;
  const int nt = blockIdx.x, ot = blockIdx.y, b = blockIdx.z;
  f32x4 acc[4][4];
#pragma unroll
  for (int m = 0; m < 4; ++m)
#pragma unroll
    for (int nq = 0; nq < 4; ++nq) acc[m][nq] = (f32x4){0.f, 0.f, 0.f, 0.f};
  const char* Ap = xt + ((size_t)b * NN + (size_t)nt * 128) * 512;
  const char* Bp = fb + ((size_t)(b * 256 + ot * 128)) * 512;
  gemm_core(Ap, 512, Bp, 512, 4, smem, tid, acc);
  const int w = tid >> 6, l = tid & 63, wm = w >> 1, wn = w & 1;
#pragma unroll
  for (int m = 0; m < 4; ++m)
#pragma unroll
    for (int nq = 0; nq < 4; ++nq)
#pragma unroll
      for (int r = 0; r < 4; ++r) {
        int i = wm * 64 + m * 16 + ((l >> 4) << 2) + r;  // n_local (A row)
        int j = wn * 64 + nq * 16 + (l & 15);            // o_local (B row)
        *(float*)(smem + j * 512 + ((i * 4) ^ ((j & 7) << 4))) = acc[m][nq][r];
      }
  __syncthreads();
  const int j = tid >> 1, h = tid & 1;
  float* dst = out + ((size_t)(b * 256 + ot * 128 + j)) * NN + nt * 128;
#pragma unroll
  for (int cc = 0; cc < 16; ++cc) {
    int ch = h * 16 + cc;
    *(uint4*)(dst + ch * 4) =
        *(const uint4*)(smem + j * 512 + ((ch * 16) ^ ((j & 7) << 4)));
  }
}

extern "C" void kernel_launch(void* const* d_in, const int* in_sizes, int n_in,
                              void* d_out, int out_size, void* d_ws, size_t ws_size,
                              hipStream_t stream) {
  const float* x     = (const float*)d_in[0];
  const float* wqkv  = (const float*)d_in[1];
  const float* wdwf  = (const float*)d_in[2];
  const float* temp  = (const float*)d_in[3];
  const float* wproj = (const float*)d_in[4];
  float* out = (float*)d_out;
  char* ws = (char*)d_ws;

  // Workspace layout (bytes); total ~145 MB
  char*  xt    = ws;                            // bf16 [B][N][C]      67,108,864
  float* gpart = (float*)(ws + 67108864);       // f32 [32][B][256][256] 67,108,864
  float* G     = (float*)(ws + 134217728);      // f32 [B][256][256]    2,097,152
  float* T12   = (float*)(ws + 136314880);      // f32 [B][512][256]    4,194,304
  float* attn  = (float*)(ws + 140509184);      // f32 [B][256][256]    2,097,152
  char*  Fb    = ws + 142606336;                // bf16 [B][256][256]   1,048,576
  float* Wcat  = (float*)(ws + 143654912);      // f32 [512][256]         524,288
  float* WkT   = (float*)(ws + 144179200);      // f32 [256][256]         262,144
  float* Wv2   = (float*)(ws + 144441344);      // f32 [256][256]         262,144
  float* nqk   = (float*)(ws + 144703488);      // f32 [B][512]            16,384

  k_prepw2<<<dim3(256), dim3(256), 0, stream>>>(wqkv, wdwf, Wcat, WkT, Wv2);
  // fused gram + transpose-convert: x read ONCE; xb/k_convert deleted
  k_gramT<<<dim3(KS, NB), dim3(512), 0, stream>>>(x, gpart, xt);
  k_reduceG<<<dim3(256, NB), dim3(256), 0, stream>>>(gpart, G);
  k_sgT<<<dim3(64, NB), dim3(256), 0, stream>>>(Wcat, G, T12, nqk);
  k_ssoft<<<dim3(32, NB), dim3(256), 0, stream>>>(T12, WkT, nqk, temp, attn);
  k_sg2x<<<dim3(32, NB), dim3(256), 0, stream>>>(wproj, attn, Wv2, Fb);
  k_final<<<dim3(128, 2, NB), dim3(256), 0, stream>>>(xt, Fb, out);
}